// Round 11
// baseline (369.055 us; speedup 1.0000x reference)
//
#include <hip/hip_runtime.h>
#include <hip/hip_bf16.h>

#define NPIX (512 * 512)
#define IMW 512
#define IMH 512
#define NBINS 64  // 8x8 bins of 64x64 px sample-space

typedef float fvec4 __attribute__((ext_vector_type(4)));

static __device__ __forceinline__ unsigned short f2bf(float f) {
  union { __hip_bfloat16 h; unsigned short u; } cv;
  cv.h = __float2bfloat16(f);  // RNE
  return cv.u;
}
static __device__ __forceinline__ unsigned pack2bf(float lo, float hi) {
  return (unsigned)f2bf(lo) | ((unsigned)f2bf(hi) << 16);
}
static __device__ __forceinline__ float bflo(unsigned u) {
  return __uint_as_float(u << 16);
}
static __device__ __forceinline__ float bfhi(unsigned u) {
  return __uint_as_float(u & 0xffff0000u);
}

// ---------------------------------------------------------------------------
// Kernel 1: pointwise transforms. 5 ROLES per block (4 waves x 16 proj
// channels, 1 wave flows+wts), 64 px per block, lane == pixel.
// R4 lesson: thread-per-pixel = 4096 waves = 4 waves/SIMD -> latency-bound at
// VALUBusy 53%. Role-split gives 20480 waves (5x) with same-block roles
// sharing input reads through L1. Each role's live set is ~28 regs (no spill).
// ---------------------------------------------------------------------------
__global__ __launch_bounds__(320) void k1_pointwise(
    const float* __restrict__ in, const float* __restrict__ conv_w,
    const float* __restrict__ conv_b, const float* __restrict__ offset_w,
    const float* __restrict__ offset_b, const float* __restrict__ wconv_w,
    const float* __restrict__ wconv_b, __hip_bfloat16* __restrict__ proj_t,
    __hip_bfloat16* __restrict__ flows_t, float* __restrict__ wts_t) {
  const int role = threadIdx.x >> 6;  // wave-uniform
  const int n = blockIdx.x * 64 + (threadIdx.x & 63);

  if (role < 4) {
    // proj channels [16*role, 16*role+16)
    const float* wbase = conv_w + role * 16 * 64;
    const float* bbase = conv_b + role * 16;
    float acc[16];
#pragma unroll
    for (int o = 0; o < 16; ++o) acc[o] = bbase[o];
#pragma unroll 1
    for (int cb = 0; cb < 64; cb += 8) {
      float x[8];
#pragma unroll
      for (int j = 0; j < 8; ++j) x[j] = in[(size_t)(cb + j) * NPIX + n];
#pragma unroll
      for (int o = 0; o < 16; ++o) {
#pragma unroll
        for (int j = 0; j < 8; ++j)
          acc[o] = fmaf(x[j], wbase[o * 64 + cb + j], acc[o]);
      }
    }
    uint4 v0, v1;
    v0.x = pack2bf(acc[0], acc[1]);   v0.y = pack2bf(acc[2], acc[3]);
    v0.z = pack2bf(acc[4], acc[5]);   v0.w = pack2bf(acc[6], acc[7]);
    v1.x = pack2bf(acc[8], acc[9]);   v1.y = pack2bf(acc[10], acc[11]);
    v1.z = pack2bf(acc[12], acc[13]); v1.w = pack2bf(acc[14], acc[15]);
    uint4* pj = (uint4*)(proj_t + (size_t)n * 64 + role * 16);
    pj[0] = v0;
    pj[1] = v1;
  } else {
    // flows (8) + weight logits (4) + softmax
    float acc[12];
#pragma unroll
    for (int o = 0; o < 8; ++o) acc[o] = offset_b[o];
#pragma unroll
    for (int o = 0; o < 4; ++o) acc[8 + o] = wconv_b[o];
#pragma unroll 1
    for (int cb = 0; cb < 64; cb += 8) {
      float x[8];
#pragma unroll
      for (int j = 0; j < 8; ++j) x[j] = in[(size_t)(cb + j) * NPIX + n];
#pragma unroll
      for (int o = 0; o < 8; ++o) {
#pragma unroll
        for (int j = 0; j < 8; ++j)
          acc[o] = fmaf(x[j], offset_w[o * 64 + cb + j], acc[o]);
      }
#pragma unroll
      for (int o = 0; o < 4; ++o) {
#pragma unroll
        for (int j = 0; j < 8; ++j)
          acc[8 + o] = fmaf(x[j], wconv_w[o * 64 + cb + j], acc[8 + o]);
      }
    }
    uint4 fv;
    fv.x = pack2bf(acc[0], acc[1]);  // k0: (x,y)
    fv.y = pack2bf(acc[2], acc[3]);  // k1
    fv.z = pack2bf(acc[4], acc[5]);  // k2
    fv.w = pack2bf(acc[6], acc[7]);  // k3
    *(uint4*)(flows_t + (size_t)n * 8) = fv;

    const float m = fmaxf(fmaxf(acc[8], acc[9]), fmaxf(acc[10], acc[11]));
    const float e0 = __expf(acc[8] - m), e1 = __expf(acc[9] - m);
    const float e2 = __expf(acc[10] - m), e3 = __expf(acc[11] - m);
    const float inv = 1.f / (e0 + e1 + e2 + e3);
    *(float4*)(wts_t + (size_t)n * 4) =
        make_float4(e0 * inv, e1 * inv, e2 * inv, e3 * inv);
  }
}

static __device__ __forceinline__ int bin_of(float axv, float ayv) {
  const int ix = (int)axv, iy = (int)ayv;  // [0,510]
  return ((iy >> 6) << 3) | (ix >> 6);
}

// ---- binning: histogram -> serial scan -> two-level scatter ---------------
__global__ __launch_bounds__(256) void k2a_hist(const float* __restrict__ ax,
                                                const float* __restrict__ ay,
                                                int* __restrict__ hist) {
  __shared__ int h[NBINS];
  const int t = threadIdx.x;
  if (t < NBINS) h[t] = 0;
  __syncthreads();
  const int p = blockIdx.x * 256 + t;
  atomicAdd(&h[bin_of(ax[p], ay[p])], 1);
  __syncthreads();
  if (t < NBINS && h[t] > 0) atomicAdd(&hist[t], h[t]);
}

__global__ void k2b_scan(const int* __restrict__ hist,
                         int* __restrict__ cursor) {
  if (threadIdx.x == 0) {
    int run = 0;
    for (int b = 0; b < NBINS; ++b) {
      cursor[b] = run;
      run += hist[b];
    }
  }
}

__global__ __launch_bounds__(256) void k2c_scatter(
    const float* __restrict__ ax, const float* __restrict__ ay,
    int* __restrict__ cursor, int* __restrict__ order) {
  __shared__ int h[NBINS], base[NBINS], off[NBINS];
  const int t = threadIdx.x;
  if (t < NBINS) { h[t] = 0; off[t] = 0; }
  __syncthreads();
  const int p = blockIdx.x * 256 + t;
  const int b = bin_of(ax[p], ay[p]);
  atomicAdd(&h[b], 1);
  __syncthreads();
  if (t < NBINS && h[t] > 0) base[t] = atomicAdd(&cursor[t], h[t]);
  __syncthreads();
  const int r = atomicAdd(&off[b], 1);
  order[base[b] + r] = p;
}

// ---------------------------------------------------------------------------
// Kernel 2d: the gather, in BIN ORDER. Blocks walk order[] so all pixels in a
// block sample from one 64x64-px tile (proj slice 512 KB). The bijective
// bid%8 swizzle gives each XCD a contiguous chunk of bin-space -> per-XCD
// gather working set ~2 MB -> L2-resident (this was the invariant ~130 us
// wall: proj 32MB >> 4MB/XCD L2 made every random gather an L2 miss).
// Output goes to pixel-major bf16 staging (binned pixels can't write
// channel-major coalesced); k3 transposes.
// ---------------------------------------------------------------------------
__global__ __launch_bounds__(256) void k2d_sample(
    const float* __restrict__ ax, const float* __restrict__ ay,
    const __hip_bfloat16* __restrict__ proj_t,
    const __hip_bfloat16* __restrict__ flows_t,
    const float* __restrict__ wts_t, const int* __restrict__ order,
    __hip_bfloat16* __restrict__ outp) {
  const int t = threadIdx.x;
  const int g8 = t >> 3, l8 = t & 7;
  const int bid = blockIdx.x;
  const int chunk = (bid & 7) * (NPIX / 64 / 8) + (bid >> 3);  // XCD-contig

#pragma unroll 1
  for (int pass = 0; pass < 2; ++pass) {
    const int pid = order[chunk * 64 + pass * 32 + g8];
    const float axv = ax[pid], ayv = ay[pid];
    const float4 wk4 = *(const float4*)(wts_t + (size_t)pid * 4);
    const size_t n2 = (size_t)((int)ayv * IMW + (int)axv);
    const uint4 fw = *(const uint4*)(flows_t + n2 * 8);
    const float fx[4] = {bflo(fw.x), bflo(fw.y), bflo(fw.z), bflo(fw.w)};
    const float fy[4] = {bfhi(fw.x), bfhi(fw.y), bfhi(fw.z), bfhi(fw.w)};
    const float wk[4] = {wk4.x, wk4.y, wk4.z, wk4.w};

    float acc[8];
#pragma unroll
    for (int j = 0; j < 8; ++j) acc[j] = 0.f;

#pragma unroll
    for (int k = 0; k < 4; ++k) {
      const float xs = (axv + fx[k]) * (512.f / 511.f) - 0.5f;
      const float ys = (ayv + fy[k]) * (512.f / 511.f) - 0.5f;
      const float x0f = floorf(xs), y0f = floorf(ys);
      const float wx = xs - x0f, wy = ys - y0f;
      const int x0 = (int)x0f, y0 = (int)y0f;
      const int x1 = x0 + 1, y1 = y0 + 1;
      const int cx0 = min(max(x0, 0), IMW - 1);
      const int cx1 = min(max(x1, 0), IMW - 1);
      const int cy0 = min(max(y0, 0), IMH - 1);
      const int cy1 = min(max(y1, 0), IMH - 1);
      const float vx0 = (x0 >= 0 && x0 < IMW) ? 1.f : 0.f;
      const float vx1 = (x1 >= 0 && x1 < IMW) ? 1.f : 0.f;
      const float vy0 = (y0 >= 0 && y0 < IMH) ? 1.f : 0.f;
      const float vy1 = (y1 >= 0 && y1 < IMH) ? 1.f : 0.f;
      const float s00 = wk[k] * (1.f - wx) * (1.f - wy) * vx0 * vy0;
      const float s10 = wk[k] * wx * (1.f - wy) * vx1 * vy0;
      const float s01 = wk[k] * (1.f - wx) * wy * vx0 * vy1;
      const float s11 = wk[k] * wx * wy * vx1 * vy1;

      const uint4 u00 = *(const uint4*)(proj_t + (size_t)(cy0 * IMW + cx0) * 64 + l8 * 8);
      const uint4 u10 = *(const uint4*)(proj_t + (size_t)(cy0 * IMW + cx1) * 64 + l8 * 8);
      const uint4 u01 = *(const uint4*)(proj_t + (size_t)(cy1 * IMW + cx0) * 64 + l8 * 8);
      const uint4 u11 = *(const uint4*)(proj_t + (size_t)(cy1 * IMW + cx1) * 64 + l8 * 8);

      const unsigned w00[4] = {u00.x, u00.y, u00.z, u00.w};
      const unsigned w10[4] = {u10.x, u10.y, u10.z, u10.w};
      const unsigned w01[4] = {u01.x, u01.y, u01.z, u01.w};
      const unsigned w11[4] = {u11.x, u11.y, u11.z, u11.w};
#pragma unroll
      for (int q = 0; q < 4; ++q) {
        acc[2 * q] = fmaf(bflo(w00[q]), s00, acc[2 * q]);
        acc[2 * q] = fmaf(bflo(w10[q]), s10, acc[2 * q]);
        acc[2 * q] = fmaf(bflo(w01[q]), s01, acc[2 * q]);
        acc[2 * q] = fmaf(bflo(w11[q]), s11, acc[2 * q]);
        acc[2 * q + 1] = fmaf(bfhi(w00[q]), s00, acc[2 * q + 1]);
        acc[2 * q + 1] = fmaf(bfhi(w10[q]), s10, acc[2 * q + 1]);
        acc[2 * q + 1] = fmaf(bfhi(w01[q]), s01, acc[2 * q + 1]);
        acc[2 * q + 1] = fmaf(bfhi(w11[q]), s11, acc[2 * q + 1]);
      }
    }
    // pixel-major bf16 staging: group's 8 lanes write contiguous 128 B
    uint4 o;
    o.x = pack2bf(acc[0], acc[1]);
    o.y = pack2bf(acc[2], acc[3]);
    o.z = pack2bf(acc[4], acc[5]);
    o.w = pack2bf(acc[6], acc[7]);
    *(uint4*)(outp + (size_t)pid * 64 + l8 * 8) = o;
  }
}

// ---------------------------------------------------------------------------
// Kernel 3: pixel-major bf16 staging -> channel-major f32 output.
// Both sides coalesced via LDS tile; nontemporal stores (streamed, no reuse).
// ---------------------------------------------------------------------------
__global__ __launch_bounds__(256) void k3_transpose(
    const __hip_bfloat16* __restrict__ outp, float* __restrict__ out) {
  __shared__ float tile[64][68];
  const int t = threadIdx.x;
  const int g8 = t >> 3, l8 = t & 7;
  const int p0 = blockIdx.x * 64;
#pragma unroll
  for (int pass = 0; pass < 2; ++pass) {
    const int pl = pass * 32 + g8;
    const uint4 u = *(const uint4*)(outp + (size_t)(p0 + pl) * 64 + l8 * 8);
    float* dst = &tile[pl][8 * l8];
    dst[0] = bflo(u.x); dst[1] = bfhi(u.x);
    dst[2] = bflo(u.y); dst[3] = bfhi(u.y);
    dst[4] = bflo(u.z); dst[5] = bfhi(u.z);
    dst[6] = bflo(u.w); dst[7] = bfhi(u.w);
  }
  __syncthreads();
  const int g16 = t >> 4, l16 = t & 15;
#pragma unroll
  for (int it = 0; it < 4; ++it) {
    const int c = it * 16 + g16;
    fvec4 vv;
    vv.x = tile[4 * l16 + 0][c];
    vv.y = tile[4 * l16 + 1][c];
    vv.z = tile[4 * l16 + 2][c];
    vv.w = tile[4 * l16 + 3][c];
    __builtin_nontemporal_store(
        vv, (fvec4*)(out + (size_t)c * NPIX + p0 + 4 * l16));
  }
}

extern "C" void kernel_launch(void* const* d_in, const int* in_sizes, int n_in,
                              void* d_out, int out_size, void* d_ws,
                              size_t ws_size, hipStream_t stream) {
  const float* input = (const float*)d_in[0];
  const float* ax = (const float*)d_in[1];
  const float* ay = (const float*)d_in[2];
  const float* conv_w = (const float*)d_in[3];
  const float* conv_b = (const float*)d_in[4];
  const float* offset_w = (const float*)d_in[5];
  const float* offset_b = (const float*)d_in[6];
  const float* wconv_w = (const float*)d_in[7];
  const float* wconv_b = (const float*)d_in[8];
  float* out = (float*)d_out;

  // ws layout: 32 + 32 + 4 + 4 + 1 MiB + 512 B = 73.0 MiB (<76 known-good)
  __hip_bfloat16* proj_t = (__hip_bfloat16*)d_ws;          // [N][64] bf16
  __hip_bfloat16* outp = proj_t + (size_t)NPIX * 64;       // [N][64] bf16
  __hip_bfloat16* flows_t = outp + (size_t)NPIX * 64;      // [N][8]  bf16
  float* wts_t = (float*)(flows_t + (size_t)NPIX * 8);     // [N][4]  f32
  int* order = (int*)(wts_t + (size_t)NPIX * 4);           // [N]
  int* hist = order + NPIX;                                // [64]
  int* cursor = hist + NBINS;                              // [64]

  hipMemsetAsync(hist, 0, 2 * NBINS * sizeof(int), stream);
  hipLaunchKernelGGL(k1_pointwise, dim3(NPIX / 64), dim3(320), 0, stream,
                     input, conv_w, conv_b, offset_w, offset_b, wconv_w,
                     wconv_b, proj_t, flows_t, wts_t);
  hipLaunchKernelGGL(k2a_hist, dim3(NPIX / 256), dim3(256), 0, stream, ax, ay,
                     hist);
  hipLaunchKernelGGL(k2b_scan, dim3(1), dim3(64), 0, stream, hist, cursor);
  hipLaunchKernelGGL(k2c_scatter, dim3(NPIX / 256), dim3(256), 0, stream, ax,
                     ay, cursor, order);
  hipLaunchKernelGGL(k2d_sample, dim3(NPIX / 64), dim3(256), 0, stream, ax, ay,
                     proj_t, flows_t, wts_t, order, outp);
  hipLaunchKernelGGL(k3_transpose, dim3(NPIX / 64), dim3(256), 0, stream, outp,
                     out);
}

// Round 13
// 301.604 us; speedup vs baseline: 1.2236x; 1.2236x over previous
//
#include <hip/hip_runtime.h>
#include <hip/hip_bf16.h>

#define NPIX (512 * 512)
#define IMW 512
#define IMH 512
#define NBINS 64  // 8x8 bins of 64x64 px sample-space

typedef float fvec4 __attribute__((ext_vector_type(4)));

static __device__ __forceinline__ unsigned short f2bf(float f) {
  union { __hip_bfloat16 h; unsigned short u; } cv;
  cv.h = __float2bfloat16(f);  // RNE
  return cv.u;
}
static __device__ __forceinline__ unsigned pack2bf(float lo, float hi) {
  return (unsigned)f2bf(lo) | ((unsigned)f2bf(hi) << 16);
}
static __device__ __forceinline__ float bflo(unsigned u) {
  return __uint_as_float(u << 16);
}
static __device__ __forceinline__ float bfhi(unsigned u) {
  return __uint_as_float(u & 0xffff0000u);
}

// ---------------------------------------------------------------------------
// Kernel 1: pointwise transforms — r4's proven 3-pass thread-per-pixel
// structure, split across blockIdx.y to double wave count.
//   half 0: proj ch 0..31 (pass A) + flows (pass B)
//   half 1: proj ch 32..63 (pass A) + logits+softmax (pass B)
// R11 lesson: 320-thread role-split blocks got ~2 blocks/CU (Occupancy 33%,
// VALU 24%) — regression. This keeps 256-thread blocks (r4-proven residency)
// and doubles occupancy via grid: 8192 waves = 8/SIMD vs r4's 4. Per-pass
// live set identical to r4 (acc[32]+x[8], VGPR ~36-56, no spill).
// ---------------------------------------------------------------------------
__global__ __launch_bounds__(256) void k1_pointwise(
    const float* __restrict__ in, const float* __restrict__ conv_w,
    const float* __restrict__ conv_b, const float* __restrict__ offset_w,
    const float* __restrict__ offset_b, const float* __restrict__ wconv_w,
    const float* __restrict__ wconv_b, __hip_bfloat16* __restrict__ proj_t,
    __hip_bfloat16* __restrict__ flows_t, float* __restrict__ wts_t) {
  const int n = blockIdx.x * 256 + threadIdx.x;
  const int half = blockIdx.y;  // 0 or 1, wave-uniform

  // ---- pass A: proj output channels [32*half, 32*half+32) ----
  {
    const float* wbase = conv_w + half * 32 * 64;
    const float* bbase = conv_b + half * 32;
    float acc[32];
#pragma unroll
    for (int o = 0; o < 32; ++o) acc[o] = bbase[o];
#pragma unroll 1
    for (int cb = 0; cb < 64; cb += 8) {
      float x[8];
#pragma unroll
      for (int j = 0; j < 8; ++j) x[j] = in[(size_t)(cb + j) * NPIX + n];
#pragma unroll
      for (int o = 0; o < 32; ++o) {
#pragma unroll
        for (int j = 0; j < 8; ++j)
          acc[o] = fmaf(x[j], wbase[o * 64 + cb + j], acc[o]);
      }
    }
    uint4* pj = (uint4*)(proj_t + (size_t)n * 64 + half * 32);
    uint4 v0, v1, v2, v3;
    v0.x = pack2bf(acc[0], acc[1]);   v0.y = pack2bf(acc[2], acc[3]);
    v0.z = pack2bf(acc[4], acc[5]);   v0.w = pack2bf(acc[6], acc[7]);
    v1.x = pack2bf(acc[8], acc[9]);   v1.y = pack2bf(acc[10], acc[11]);
    v1.z = pack2bf(acc[12], acc[13]); v1.w = pack2bf(acc[14], acc[15]);
    v2.x = pack2bf(acc[16], acc[17]); v2.y = pack2bf(acc[18], acc[19]);
    v2.z = pack2bf(acc[20], acc[21]); v2.w = pack2bf(acc[22], acc[23]);
    v3.x = pack2bf(acc[24], acc[25]); v3.y = pack2bf(acc[26], acc[27]);
    v3.z = pack2bf(acc[28], acc[29]); v3.w = pack2bf(acc[30], acc[31]);
    pj[0] = v0; pj[1] = v1; pj[2] = v2; pj[3] = v3;
  }

  // ---- pass B ----
  if (half == 0) {
    // flows: 8 outputs
    float acc[8];
#pragma unroll
    for (int o = 0; o < 8; ++o) acc[o] = offset_b[o];
#pragma unroll 1
    for (int cb = 0; cb < 64; cb += 8) {
      float x[8];
#pragma unroll
      for (int j = 0; j < 8; ++j) x[j] = in[(size_t)(cb + j) * NPIX + n];
#pragma unroll
      for (int o = 0; o < 8; ++o) {
#pragma unroll
        for (int j = 0; j < 8; ++j)
          acc[o] = fmaf(x[j], offset_w[o * 64 + cb + j], acc[o]);
      }
    }
    uint4 fv;
    fv.x = pack2bf(acc[0], acc[1]);  // k0: (x,y)
    fv.y = pack2bf(acc[2], acc[3]);  // k1
    fv.z = pack2bf(acc[4], acc[5]);  // k2
    fv.w = pack2bf(acc[6], acc[7]);  // k3
    *(uint4*)(flows_t + (size_t)n * 8) = fv;
  } else {
    // weight logits (4) + softmax
    float acc[4];
#pragma unroll
    for (int o = 0; o < 4; ++o) acc[o] = wconv_b[o];
#pragma unroll 1
    for (int cb = 0; cb < 64; cb += 8) {
      float x[8];
#pragma unroll
      for (int j = 0; j < 8; ++j) x[j] = in[(size_t)(cb + j) * NPIX + n];
#pragma unroll
      for (int o = 0; o < 4; ++o) {
#pragma unroll
        for (int j = 0; j < 8; ++j)
          acc[o] = fmaf(x[j], wconv_w[o * 64 + cb + j], acc[o]);
      }
    }
    const float m = fmaxf(fmaxf(acc[0], acc[1]), fmaxf(acc[2], acc[3]));
    const float e0 = __expf(acc[0] - m), e1 = __expf(acc[1] - m);
    const float e2 = __expf(acc[2] - m), e3 = __expf(acc[3] - m);
    const float inv = 1.f / (e0 + e1 + e2 + e3);
    *(float4*)(wts_t + (size_t)n * 4) =
        make_float4(e0 * inv, e1 * inv, e2 * inv, e3 * inv);
  }
}

static __device__ __forceinline__ int bin_of(float axv, float ayv) {
  const int ix = (int)axv, iy = (int)ayv;  // [0,510]
  return ((iy >> 6) << 3) | (ix >> 6);
}

// ---- binning: histogram -> serial scan -> two-level scatter ---------------
__global__ __launch_bounds__(256) void k2a_hist(const float* __restrict__ ax,
                                                const float* __restrict__ ay,
                                                int* __restrict__ hist) {
  __shared__ int h[NBINS];
  const int t = threadIdx.x;
  if (t < NBINS) h[t] = 0;
  __syncthreads();
  const int p = blockIdx.x * 256 + t;
  atomicAdd(&h[bin_of(ax[p], ay[p])], 1);
  __syncthreads();
  if (t < NBINS && h[t] > 0) atomicAdd(&hist[t], h[t]);
}

__global__ void k2b_scan(const int* __restrict__ hist,
                         int* __restrict__ cursor) {
  if (threadIdx.x == 0) {
    int run = 0;
    for (int b = 0; b < NBINS; ++b) {
      cursor[b] = run;
      run += hist[b];
    }
  }
}

__global__ __launch_bounds__(256) void k2c_scatter(
    const float* __restrict__ ax, const float* __restrict__ ay,
    int* __restrict__ cursor, int* __restrict__ order) {
  __shared__ int h[NBINS], base[NBINS], off[NBINS];
  const int t = threadIdx.x;
  if (t < NBINS) { h[t] = 0; off[t] = 0; }
  __syncthreads();
  const int p = blockIdx.x * 256 + t;
  const int b = bin_of(ax[p], ay[p]);
  atomicAdd(&h[b], 1);
  __syncthreads();
  if (t < NBINS && h[t] > 0) base[t] = atomicAdd(&cursor[t], h[t]);
  __syncthreads();
  const int r = atomicAdd(&off[b], 1);
  order[base[b] + r] = p;
}

// ---------------------------------------------------------------------------
// Kernel 2d: the gather, in BIN ORDER (unchanged from r11 so its dispatch
// duration — now visible with k1 fast — decomposes the r11 k2-chain time).
// ---------------------------------------------------------------------------
__global__ __launch_bounds__(256) void k2d_sample(
    const float* __restrict__ ax, const float* __restrict__ ay,
    const __hip_bfloat16* __restrict__ proj_t,
    const __hip_bfloat16* __restrict__ flows_t,
    const float* __restrict__ wts_t, const int* __restrict__ order,
    __hip_bfloat16* __restrict__ outp) {
  const int t = threadIdx.x;
  const int g8 = t >> 3, l8 = t & 7;
  const int bid = blockIdx.x;
  const int chunk = (bid & 7) * (NPIX / 64 / 8) + (bid >> 3);  // XCD-contig

#pragma unroll 1
  for (int pass = 0; pass < 2; ++pass) {
    const int pid = order[chunk * 64 + pass * 32 + g8];
    const float axv = ax[pid], ayv = ay[pid];
    const float4 wk4 = *(const float4*)(wts_t + (size_t)pid * 4);
    const size_t n2 = (size_t)((int)ayv * IMW + (int)axv);
    const uint4 fw = *(const uint4*)(flows_t + n2 * 8);
    const float fx[4] = {bflo(fw.x), bflo(fw.y), bflo(fw.z), bflo(fw.w)};
    const float fy[4] = {bfhi(fw.x), bfhi(fw.y), bfhi(fw.z), bfhi(fw.w)};
    const float wk[4] = {wk4.x, wk4.y, wk4.z, wk4.w};

    float acc[8];
#pragma unroll
    for (int j = 0; j < 8; ++j) acc[j] = 0.f;

#pragma unroll
    for (int k = 0; k < 4; ++k) {
      const float xs = (axv + fx[k]) * (512.f / 511.f) - 0.5f;
      const float ys = (ayv + fy[k]) * (512.f / 511.f) - 0.5f;
      const float x0f = floorf(xs), y0f = floorf(ys);
      const float wx = xs - x0f, wy = ys - y0f;
      const int x0 = (int)x0f, y0 = (int)y0f;
      const int x1 = x0 + 1, y1 = y0 + 1;
      const int cx0 = min(max(x0, 0), IMW - 1);
      const int cx1 = min(max(x1, 0), IMW - 1);
      const int cy0 = min(max(y0, 0), IMH - 1);
      const int cy1 = min(max(y1, 0), IMH - 1);
      const float vx0 = (x0 >= 0 && x0 < IMW) ? 1.f : 0.f;
      const float vx1 = (x1 >= 0 && x1 < IMW) ? 1.f : 0.f;
      const float vy0 = (y0 >= 0 && y0 < IMH) ? 1.f : 0.f;
      const float vy1 = (y1 >= 0 && y1 < IMH) ? 1.f : 0.f;
      const float s00 = wk[k] * (1.f - wx) * (1.f - wy) * vx0 * vy0;
      const float s10 = wk[k] * wx * (1.f - wy) * vx1 * vy0;
      const float s01 = wk[k] * (1.f - wx) * wy * vx0 * vy1;
      const float s11 = wk[k] * wx * wy * vx1 * vy1;

      const uint4 u00 = *(const uint4*)(proj_t + (size_t)(cy0 * IMW + cx0) * 64 + l8 * 8);
      const uint4 u10 = *(const uint4*)(proj_t + (size_t)(cy0 * IMW + cx1) * 64 + l8 * 8);
      const uint4 u01 = *(const uint4*)(proj_t + (size_t)(cy1 * IMW + cx0) * 64 + l8 * 8);
      const uint4 u11 = *(const uint4*)(proj_t + (size_t)(cy1 * IMW + cx1) * 64 + l8 * 8);

      const unsigned w00[4] = {u00.x, u00.y, u00.z, u00.w};
      const unsigned w10[4] = {u10.x, u10.y, u10.z, u10.w};
      const unsigned w01[4] = {u01.x, u01.y, u01.z, u01.w};
      const unsigned w11[4] = {u11.x, u11.y, u11.z, u11.w};
#pragma unroll
      for (int q = 0; q < 4; ++q) {
        acc[2 * q] = fmaf(bflo(w00[q]), s00, acc[2 * q]);
        acc[2 * q] = fmaf(bflo(w10[q]), s10, acc[2 * q]);
        acc[2 * q] = fmaf(bflo(w01[q]), s01, acc[2 * q]);
        acc[2 * q] = fmaf(bflo(w11[q]), s11, acc[2 * q]);
        acc[2 * q + 1] = fmaf(bfhi(w00[q]), s00, acc[2 * q + 1]);
        acc[2 * q + 1] = fmaf(bfhi(w10[q]), s10, acc[2 * q + 1]);
        acc[2 * q + 1] = fmaf(bfhi(w01[q]), s01, acc[2 * q + 1]);
        acc[2 * q + 1] = fmaf(bfhi(w11[q]), s11, acc[2 * q + 1]);
      }
    }
    // pixel-major bf16 staging: group's 8 lanes write contiguous 128 B
    uint4 o;
    o.x = pack2bf(acc[0], acc[1]);
    o.y = pack2bf(acc[2], acc[3]);
    o.z = pack2bf(acc[4], acc[5]);
    o.w = pack2bf(acc[6], acc[7]);
    *(uint4*)(outp + (size_t)pid * 64 + l8 * 8) = o;
  }
}

// ---------------------------------------------------------------------------
// Kernel 3: pixel-major bf16 staging -> channel-major f32 output.
// ---------------------------------------------------------------------------
__global__ __launch_bounds__(256) void k3_transpose(
    const __hip_bfloat16* __restrict__ outp, float* __restrict__ out) {
  __shared__ float tile[64][68];
  const int t = threadIdx.x;
  const int g8 = t >> 3, l8 = t & 7;
  const int p0 = blockIdx.x * 64;
#pragma unroll
  for (int pass = 0; pass < 2; ++pass) {
    const int pl = pass * 32 + g8;
    const uint4 u = *(const uint4*)(outp + (size_t)(p0 + pl) * 64 + l8 * 8);
    float* dst = &tile[pl][8 * l8];
    dst[0] = bflo(u.x); dst[1] = bfhi(u.x);
    dst[2] = bflo(u.y); dst[3] = bfhi(u.y);
    dst[4] = bflo(u.z); dst[5] = bfhi(u.z);
    dst[6] = bflo(u.w); dst[7] = bfhi(u.w);
  }
  __syncthreads();
  const int g16 = t >> 4, l16 = t & 15;
#pragma unroll
  for (int it = 0; it < 4; ++it) {
    const int c = it * 16 + g16;
    fvec4 vv;
    vv.x = tile[4 * l16 + 0][c];
    vv.y = tile[4 * l16 + 1][c];
    vv.z = tile[4 * l16 + 2][c];
    vv.w = tile[4 * l16 + 3][c];
    __builtin_nontemporal_store(
        vv, (fvec4*)(out + (size_t)c * NPIX + p0 + 4 * l16));
  }
}

extern "C" void kernel_launch(void* const* d_in, const int* in_sizes, int n_in,
                              void* d_out, int out_size, void* d_ws,
                              size_t ws_size, hipStream_t stream) {
  const float* input = (const float*)d_in[0];
  const float* ax = (const float*)d_in[1];
  const float* ay = (const float*)d_in[2];
  const float* conv_w = (const float*)d_in[3];
  const float* conv_b = (const float*)d_in[4];
  const float* offset_w = (const float*)d_in[5];
  const float* offset_b = (const float*)d_in[6];
  const float* wconv_w = (const float*)d_in[7];
  const float* wconv_b = (const float*)d_in[8];
  float* out = (float*)d_out;

  // ws layout: 32 + 32 + 4 + 4 + 1 MiB + 512 B = 73.0 MiB (<76 known-good)
  __hip_bfloat16* proj_t = (__hip_bfloat16*)d_ws;          // [N][64] bf16
  __hip_bfloat16* outp = proj_t + (size_t)NPIX * 64;       // [N][64] bf16
  __hip_bfloat16* flows_t = outp + (size_t)NPIX * 64;      // [N][8]  bf16
  float* wts_t = (float*)(flows_t + (size_t)NPIX * 8);     // [N][4]  f32
  int* order = (int*)(wts_t + (size_t)NPIX * 4);           // [N]
  int* hist = order + NPIX;                                // [64]
  int* cursor = hist + NBINS;                              // [64]

  hipMemsetAsync(hist, 0, 2 * NBINS * sizeof(int), stream);
  hipLaunchKernelGGL(k1_pointwise, dim3(NPIX / 256, 2), dim3(256), 0, stream,
                     input, conv_w, conv_b, offset_w, offset_b, wconv_w,
                     wconv_b, proj_t, flows_t, wts_t);
  hipLaunchKernelGGL(k2a_hist, dim3(NPIX / 256), dim3(256), 0, stream, ax, ay,
                     hist);
  hipLaunchKernelGGL(k2b_scan, dim3(1), dim3(64), 0, stream, hist, cursor);
  hipLaunchKernelGGL(k2c_scatter, dim3(NPIX / 256), dim3(256), 0, stream, ax,
                     ay, cursor, order);
  hipLaunchKernelGGL(k2d_sample, dim3(NPIX / 64), dim3(256), 0, stream, ax, ay,
                     proj_t, flows_t, wts_t, order, outp);
  hipLaunchKernelGGL(k3_transpose, dim3(NPIX / 64), dim3(256), 0, stream, outp,
                     out);
}

// Round 14
// 213.715 us; speedup vs baseline: 1.7269x; 1.4112x over previous
//
#include <hip/hip_runtime.h>
#include <hip/hip_bf16.h>

#define NPIX (512 * 512)
#define IMW 512
#define IMH 512

typedef float fvec4 __attribute__((ext_vector_type(4)));
typedef short bf16x8 __attribute__((ext_vector_type(8)));
typedef float f32x4 __attribute__((ext_vector_type(4)));

static __device__ __forceinline__ unsigned short f2bf(float f) {
  union { __hip_bfloat16 h; unsigned short u; } cv;
  cv.h = __float2bfloat16(f);  // RNE
  return cv.u;
}
static __device__ __forceinline__ unsigned pack2bf(float lo, float hi) {
  return (unsigned)f2bf(lo) | ((unsigned)f2bf(hi) << 16);
}
static __device__ __forceinline__ float bflo(unsigned u) {
  return __uint_as_float(u << 16);
}
static __device__ __forceinline__ float bfhi(unsigned u) {
  return __uint_as_float(u & 0xffff0000u);
}

// ---------------------------------------------------------------------------
// Kernel A: proj via MFMA. r13 evidence: scalar GEMV pins VALU issue at ~53%
// regardless of occupancy (108us r4 @28%, 111us r13 @48%) with ~3x the
// necessary VALU work — structural exit is the matrix pipe.
// Per wave: 16 pixels x 64 outputs, mfma_f32_16x16x32_bf16:
//   A (16px x 32ch): lane = px(l&15), ch (l>>4)*8+j  [j=0..7]
//   B (32ch x 16out): lane = out(l&15), ch (l>>4)*8+j
//   C/D: col(out)=lane&15, row(px)=(lane>>4)*4+reg   [verified layout, §3]
// Bias folded into C-init (all 4 rows of col n get conv_b[n]).
// B-fragments built once per wave from the 16KB conv_w (L1/L2-resident).
// C stored as 2B scatter: each store inst = 4 x 32B full sectors.
// ---------------------------------------------------------------------------
__global__ __launch_bounds__(256) void k1_proj_mfma(
    const float* __restrict__ in, const float* __restrict__ conv_w,
    const float* __restrict__ conv_b, __hip_bfloat16* __restrict__ proj_t) {
  const int wave = threadIdx.x >> 6;
  const int l = threadIdx.x & 63;
  const int px0 = blockIdx.x * 64 + wave * 16;
  const int lc = l & 15;   // A: pixel-in-tile; B: out-channel-in-tile; C: col
  const int kg = l >> 4;   // k-group (8 channels) / C row-group

  // B fragments: [kstep][ntile]
  bf16x8 bf[2][4];
#pragma unroll
  for (int t = 0; t < 2; ++t) {
#pragma unroll
    for (int nt = 0; nt < 4; ++nt) {
      const float* wr = conv_w + (size_t)(nt * 16 + lc) * 64 + t * 32 + kg * 8;
      const float4 w0 = *(const float4*)(wr);
      const float4 w1 = *(const float4*)(wr + 4);
      bf16x8 f;
      f[0] = (short)f2bf(w0.x); f[1] = (short)f2bf(w0.y);
      f[2] = (short)f2bf(w0.z); f[3] = (short)f2bf(w0.w);
      f[4] = (short)f2bf(w1.x); f[5] = (short)f2bf(w1.y);
      f[6] = (short)f2bf(w1.z); f[7] = (short)f2bf(w1.w);
      bf[t][nt] = f;
    }
  }

  // C init = bias broadcast down each column
  f32x4 acc[4];
#pragma unroll
  for (int nt = 0; nt < 4; ++nt) {
    const float b = conv_b[nt * 16 + lc];
    f32x4 c; c[0] = b; c[1] = b; c[2] = b; c[3] = b;
    acc[nt] = c;
  }

#pragma unroll
  for (int t = 0; t < 2; ++t) {
    bf16x8 af;
#pragma unroll
    for (int j = 0; j < 8; ++j) {
      const float xv = in[(size_t)(t * 32 + kg * 8 + j) * NPIX + px0 + lc];
      af[j] = (short)f2bf(xv);
    }
#pragma unroll
    for (int nt = 0; nt < 4; ++nt)
      acc[nt] =
          __builtin_amdgcn_mfma_f32_16x16x32_bf16(af, bf[t][nt], acc[nt], 0, 0, 0);
  }

  // Store: lane holds col n=nt*16+lc, rows px0+kg*4+r.
#pragma unroll
  for (int nt = 0; nt < 4; ++nt) {
#pragma unroll
    for (int r = 0; r < 4; ++r) {
      const int px = px0 + kg * 4 + r;
      union { __hip_bfloat16 h; unsigned short u; } cv;
      cv.u = f2bf(acc[nt][r]);
      proj_t[(size_t)px * 64 + nt * 16 + lc] = cv.h;
    }
  }
}

// ---------------------------------------------------------------------------
// Kernel B: flows (8) + weight logits (4) + softmax. This is r4's measured
// pass-C verbatim (thread = pixel, acc[12], coalesced channel-major reads).
// ---------------------------------------------------------------------------
__global__ __launch_bounds__(256) void k1_flows(
    const float* __restrict__ in, const float* __restrict__ offset_w,
    const float* __restrict__ offset_b, const float* __restrict__ wconv_w,
    const float* __restrict__ wconv_b, __hip_bfloat16* __restrict__ flows_t,
    float* __restrict__ wts_t) {
  const int n = blockIdx.x * 256 + threadIdx.x;
  float acc[12];
#pragma unroll
  for (int o = 0; o < 8; ++o) acc[o] = offset_b[o];
#pragma unroll
  for (int o = 0; o < 4; ++o) acc[8 + o] = wconv_b[o];
#pragma unroll 1
  for (int cb = 0; cb < 64; cb += 8) {
    float x[8];
#pragma unroll
    for (int j = 0; j < 8; ++j) x[j] = in[(size_t)(cb + j) * NPIX + n];
#pragma unroll
    for (int o = 0; o < 8; ++o) {
#pragma unroll
      for (int j = 0; j < 8; ++j)
        acc[o] = fmaf(x[j], offset_w[o * 64 + cb + j], acc[o]);
    }
#pragma unroll
    for (int o = 0; o < 4; ++o) {
#pragma unroll
      for (int j = 0; j < 8; ++j)
        acc[8 + o] = fmaf(x[j], wconv_w[o * 64 + cb + j], acc[8 + o]);
    }
  }
  uint4 fv;
  fv.x = pack2bf(acc[0], acc[1]);  // k0: (x,y)
  fv.y = pack2bf(acc[2], acc[3]);  // k1
  fv.z = pack2bf(acc[4], acc[5]);  // k2
  fv.w = pack2bf(acc[6], acc[7]);  // k3
  *(uint4*)(flows_t + (size_t)n * 8) = fv;

  const float m = fmaxf(fmaxf(acc[8], acc[9]), fmaxf(acc[10], acc[11]));
  const float e0 = __expf(acc[8] - m), e1 = __expf(acc[9] - m);
  const float e2 = __expf(acc[10] - m), e3 = __expf(acc[11] - m);
  const float inv = 1.f / (e0 + e1 + e2 + e3);
  *(float4*)(wts_t + (size_t)n * 4) =
      make_float4(e0 * inv, e1 * inv, e2 * inv, e3 * inv);
}

// ---------------------------------------------------------------------------
// Kernel C: deformable bilinear gather + K-blend — r4's measured direct
// kernel (139.6us incl. all output writes), flows read patched to bf16.
// r13 verdict: binning chain = 190us > direct 139.6us — binning removed.
// 8-lane group per pixel, uint4 bf16 gathers, LDS transpose so each
// output-channel store is a 256B contiguous run; nontemporal (streamed).
// ---------------------------------------------------------------------------
static __device__ __forceinline__ void sample_one(
    float axv, float ayv, uint4 fw, float4 wk4,
    const __hip_bfloat16* __restrict__ proj_t, int l8,
    float* __restrict__ dst) {
  const float fx[4] = {bflo(fw.x), bflo(fw.y), bflo(fw.z), bflo(fw.w)};
  const float fy[4] = {bfhi(fw.x), bfhi(fw.y), bfhi(fw.z), bfhi(fw.w)};
  const float wk[4] = {wk4.x, wk4.y, wk4.z, wk4.w};

  float acc[8];
#pragma unroll
  for (int j = 0; j < 8; ++j) acc[j] = 0.f;

#pragma unroll
  for (int k = 0; k < 4; ++k) {
    const float xs = (axv + fx[k]) * (512.f / 511.f) - 0.5f;
    const float ys = (ayv + fy[k]) * (512.f / 511.f) - 0.5f;
    const float x0f = floorf(xs), y0f = floorf(ys);
    const float wx = xs - x0f, wy = ys - y0f;
    const int x0 = (int)x0f, y0 = (int)y0f;
    const int x1 = x0 + 1, y1 = y0 + 1;
    const int cx0 = min(max(x0, 0), IMW - 1);
    const int cx1 = min(max(x1, 0), IMW - 1);
    const int cy0 = min(max(y0, 0), IMH - 1);
    const int cy1 = min(max(y1, 0), IMH - 1);
    const float vx0 = (x0 >= 0 && x0 < IMW) ? 1.f : 0.f;
    const float vx1 = (x1 >= 0 && x1 < IMW) ? 1.f : 0.f;
    const float vy0 = (y0 >= 0 && y0 < IMH) ? 1.f : 0.f;
    const float vy1 = (y1 >= 0 && y1 < IMH) ? 1.f : 0.f;
    const float s00 = wk[k] * (1.f - wx) * (1.f - wy) * vx0 * vy0;
    const float s10 = wk[k] * wx * (1.f - wy) * vx1 * vy0;
    const float s01 = wk[k] * (1.f - wx) * wy * vx0 * vy1;
    const float s11 = wk[k] * wx * wy * vx1 * vy1;

    const uint4 u00 = *(const uint4*)(proj_t + (size_t)(cy0 * IMW + cx0) * 64 + l8 * 8);
    const uint4 u10 = *(const uint4*)(proj_t + (size_t)(cy0 * IMW + cx1) * 64 + l8 * 8);
    const uint4 u01 = *(const uint4*)(proj_t + (size_t)(cy1 * IMW + cx0) * 64 + l8 * 8);
    const uint4 u11 = *(const uint4*)(proj_t + (size_t)(cy1 * IMW + cx1) * 64 + l8 * 8);

    const unsigned w00[4] = {u00.x, u00.y, u00.z, u00.w};
    const unsigned w10[4] = {u10.x, u10.y, u10.z, u10.w};
    const unsigned w01[4] = {u01.x, u01.y, u01.z, u01.w};
    const unsigned w11[4] = {u11.x, u11.y, u11.z, u11.w};
#pragma unroll
    for (int q = 0; q < 4; ++q) {
      acc[2 * q] = fmaf(bflo(w00[q]), s00, acc[2 * q]);
      acc[2 * q] = fmaf(bflo(w10[q]), s10, acc[2 * q]);
      acc[2 * q] = fmaf(bflo(w01[q]), s01, acc[2 * q]);
      acc[2 * q] = fmaf(bflo(w11[q]), s11, acc[2 * q]);
      acc[2 * q + 1] = fmaf(bfhi(w00[q]), s00, acc[2 * q + 1]);
      acc[2 * q + 1] = fmaf(bfhi(w10[q]), s10, acc[2 * q + 1]);
      acc[2 * q + 1] = fmaf(bfhi(w01[q]), s01, acc[2 * q + 1]);
      acc[2 * q + 1] = fmaf(bfhi(w11[q]), s11, acc[2 * q + 1]);
    }
  }
  *(float4*)(dst) = make_float4(acc[0], acc[1], acc[2], acc[3]);
  *(float4*)(dst + 4) = make_float4(acc[4], acc[5], acc[6], acc[7]);
}

__global__ __launch_bounds__(256) void k2_sample(
    const float* __restrict__ ax, const float* __restrict__ ay,
    const __hip_bfloat16* __restrict__ proj_t,
    const __hip_bfloat16* __restrict__ flows_t,
    const float* __restrict__ wts_t, float* __restrict__ out) {
  __shared__ float tile[64][68];  // [px][ch]
  const int t = threadIdx.x;
  const int g8 = t >> 3;  // pixel within half-tile (0..31)
  const int l8 = t & 7;   // lane within group: channels 8*l8 .. 8*l8+7
  const int p0 = blockIdx.x * 64;
  const int pA = p0 + g8;
  const int pB = p0 + 32 + g8;

  // Hoisted loads: both halves' ax/ay/wts, then both flow gathers in flight.
  const float axA = ax[pA], ayA = ay[pA];
  const float axB = ax[pB], ayB = ay[pB];
  const float4 wkA = *(const float4*)(wts_t + (size_t)pA * 4);
  const float4 wkB = *(const float4*)(wts_t + (size_t)pB * 4);
  const size_t nA = (size_t)((int)ayA * IMW + (int)axA);  // trunc, ax,ay>=0
  const size_t nB = (size_t)((int)ayB * IMW + (int)axB);
  const uint4 fwA = *(const uint4*)(flows_t + nA * 8);
  const uint4 fwB = *(const uint4*)(flows_t + nB * 8);

  sample_one(axA, ayA, fwA, wkA, proj_t, l8, &tile[g8][8 * l8]);
  sample_one(axB, ayB, fwB, wkB, proj_t, l8, &tile[32 + g8][8 * l8]);
  __syncthreads();

  // Transpose-store: each output-channel row is a 256B contiguous run.
  const int g16 = t >> 4;
  const int l16 = t & 15;
#pragma unroll
  for (int it = 0; it < 4; ++it) {
    const int c = it * 16 + g16;
    fvec4 vv;
    vv.x = tile[4 * l16 + 0][c];
    vv.y = tile[4 * l16 + 1][c];
    vv.z = tile[4 * l16 + 2][c];
    vv.w = tile[4 * l16 + 3][c];
    __builtin_nontemporal_store(
        vv, (fvec4*)(out + (size_t)c * NPIX + p0 + 4 * l16));
  }
}

extern "C" void kernel_launch(void* const* d_in, const int* in_sizes, int n_in,
                              void* d_out, int out_size, void* d_ws,
                              size_t ws_size, hipStream_t stream) {
  const float* input = (const float*)d_in[0];
  const float* ax = (const float*)d_in[1];
  const float* ay = (const float*)d_in[2];
  const float* conv_w = (const float*)d_in[3];
  const float* conv_b = (const float*)d_in[4];
  const float* offset_w = (const float*)d_in[5];
  const float* offset_b = (const float*)d_in[6];
  const float* wconv_w = (const float*)d_in[7];
  const float* wconv_b = (const float*)d_in[8];
  float* out = (float*)d_out;

  // ws layout: proj 32MiB + flows 4MiB + wts 4MiB = 40 MiB
  __hip_bfloat16* proj_t = (__hip_bfloat16*)d_ws;          // [N][64] bf16
  __hip_bfloat16* flows_t = proj_t + (size_t)NPIX * 64;    // [N][8]  bf16
  float* wts_t = (float*)(flows_t + (size_t)NPIX * 8);     // [N][4]  f32

  hipLaunchKernelGGL(k1_proj_mfma, dim3(NPIX / 64), dim3(256), 0, stream,
                     input, conv_w, conv_b, proj_t);
  hipLaunchKernelGGL(k1_flows, dim3(NPIX / 256), dim3(256), 0, stream, input,
                     offset_w, offset_b, wconv_w, wconv_b, flows_t, wts_t);
  hipLaunchKernelGGL(k2_sample, dim3(NPIX / 64), dim3(256), 0, stream, ax, ay,
                     proj_t, flows_t, wts_t, out);
}